// Round 7
// baseline (379.112 us; speedup 1.0000x reference)
//
#include <hip/hip_runtime.h>
#include <cmath>

// Problem constants (from reference)
#define NN  5      // N_NODES
#define BB  4      // batch
#define CCH 256    // channels
#define HWD 1024   // H*W
#define THRESH_V 0.3f
#define EPS_V 1e-12f

// R7 = R6 (A via LDS from pre-transposed ws; X direct from global; fp32 VALU
// GEMM; (384,3) no-scratch budget) with the X prefetch deepened 1 -> 4 kk.
// R6 diagnosis: 330us wall vs 162us VALU-busy = latency stall; 1-deep
// prefetch gives ~128-256 cyc cover vs ~200-300 cyc L2 latency. Depth-4
// (named regs, unroll-4 rotation, static indices only) gives ~512+ cyc.

#define CT 64      // channel rows per block
#define WT 64      // hw cols per block
#define KC 32      // k chunk
#define APAD 68    // As/W2s row stride (floats)
#define SPAD 68    // Es row stride (floats)

#define W2T_OFF (NN * CCH * CCH)       // second table in ws

#define AS_FLOATS   (KC * APAD)        // 2176
#define ES_FLOATS   (6 * 16 * SPAD)    // 6528 (epilogue overlay, 26112 B)
#define SMEM_FLOATS ES_FLOATS

// ---------------- prep: transpose conv_w into ws (verified R3) ----------------
// ws: At[i][k][c] = W1[i][c][k] + W2[i][c][k];  W2t[i][k][c] = W2[i][c][k]
__global__ void fub_prep(const float* __restrict__ conv_w, float* __restrict__ ws)
{
    const int t = blockIdx.x * 256 + threadIdx.x;   // 0 .. 5*256*64-1
    if (t >= NN * CCH * 64) return;
    const int c4 = (t & 63) << 2;        // c base 0..252
    const int k  = (t >> 6) & 255;       // 0..255
    const int i  = t >> 14;              // 0..4
    float s1[4], s2[4];
#pragma unroll
    for (int cc = 0; cc < 4; ++cc) {
        const float* p = conv_w + (size_t)(i * CCH + c4 + cc) * (2 * CCH) + k;
        const float w1 = p[0];
        const float w2 = p[CCH];
        s1[cc] = w1 + w2;
        s2[cc] = w2;
    }
    float* At  = ws + (size_t)(i * CCH + k) * CCH + c4;
    float* W2t = ws + W2T_OFF + (size_t)(i * CCH + k) * CCH + c4;
    *(float4*)At  = make_float4(s1[0], s1[1], s1[2], s1[3]);
    *(float4*)W2t = make_float4(s2[0], s2[1], s2[2], s2[3]);
}

// X load: k index wraps at 256 (uniform AND; last-chunk prefetch reads k=0..3,
// in-bounds, values discarded)
#define XLD(V0, V1, KIDX) do {                                        \
    const float* _p = xrow + (size_t)((KIDX) & 255) * HWD;            \
    V0 = *(const float4*)_p; V1 = *(const float4*)(_p + 4);           \
} while (0)

#define FMA64(KK, X0, X1) do {                                        \
    const float4 _a0 = *(const float4*)(Mb + (KK) * APAD);            \
    const float4 _a1 = *(const float4*)(Mb + (KK) * APAD + 4);        \
    const float _ar[8] = {_a0.x,_a0.y,_a0.z,_a0.w,_a1.x,_a1.y,_a1.z,_a1.w}; \
    const float _xv[8] = {(X0).x,(X0).y,(X0).z,(X0).w,(X1).x,(X1).y,(X1).z,(X1).w}; \
    _Pragma("unroll")                                                 \
    for (int _r = 0; _r < 8; ++_r)                                    \
        _Pragma("unroll")                                             \
        for (int _c = 0; _c < 8; ++_c)                                \
            acc[_r][_c] = fmaf(_ar[_r], _xv[_c], acc[_r][_c]);        \
} while (0)

// ---------------- main ----------------
__global__ __launch_bounds__(384, 3)
void fub_main(const float* __restrict__ x, const float* __restrict__ wmat,
              const float* __restrict__ ws, const float* __restrict__ conv_b,
              float* __restrict__ out)
{
    __shared__ __align__(16) float smem[SMEM_FLOATS];
    float* As  = smem;                 // [KC][APAD]
    float* W2s = smem + AS_FLOATS;     // [KC][APAD]
    float* Es  = smem;                 // [6][16][SPAD] overlay (epilogue only)

    const int tid  = threadIdx.x;
    const int wv   = tid >> 6;        // 0..5 : stream id
    const int lane = tid & 63;

    // XCD-chunked bijective swizzle (1280 % 8 == 0): the 20 blocks sharing one
    // x panel (b,hwt) land on one XCD's L2, A tables shared across all.
    const int wg  = blockIdx.x;
    int L = (wg & 7) * 160 + (wg >> 3);
    const int i   = L % 5;  L /= 5;
    const int ct  = L & 3;  L >>= 2;
    const int b   = L & 3;  L >>= 2;
    const int hwt = L;                 // 0..15

    const int c0  = ct * CT;
    const int hw0 = hwt * WT;

    const int lr = (lane >> 3) << 3;  // frag row base 0,8,...,56
    const int lc = (lane & 7)  << 3;  // frag col base 0,8,...,56

    // stream w<5: A_i @ x[w]; stream 5: W2_i @ x[i]
    const int jx = (wv < NN) ? wv : i;
    const float* Ms = (wv == 5) ? W2s : As;
    const float* Mb = Ms + lr;
    const float* xrow = x + (size_t)((jx * BB + b) * CCH) * HWD + hw0 + lc;

    float acc[8][8];
#pragma unroll
    for (int r = 0; r < 8; ++r)
#pragma unroll
        for (int c = 0; c < 8; ++c) acc[r][c] = 0.0f;

    // 4-deep X prefetch, named registers (no runtime-indexed arrays)
    float4 xa0, xa1, xb0, xb1, xc0, xc1, xd0, xd1;
    XLD(xa0, xa1, 0);
    XLD(xb0, xb1, 1);
    XLD(xc0, xc1, 2);
    XLD(xd0, xd1, 3);

    for (int k0 = 0; k0 < CCH; k0 += KC) {
        // ---- stage A/W2 chunk from ws (coalesced float4, no transpose) ----
#pragma unroll
        for (int it = 0; it < 3; ++it) {
            const int idx = tid + it * 384;        // 0..1151, need 0..1023
            if (idx < 1024) {
                const int tbl = idx >> 9;          // 0=A, 1=W2
                const int rem = idx & 511;
                const int kk  = rem >> 4;          // 0..31
                const int c4  = (rem & 15) << 2;   // 0..60
                const float4 v = *(const float4*)(
                    ws + (size_t)(tbl ? W2T_OFF : 0)
                       + (size_t)(i * CCH + k0 + kk) * CCH + c0 + c4);
                *(float4*)((tbl ? W2s : As) + kk * APAD + c4) = v;
            }
        }
        __syncthreads();

        // ---- compute: A from LDS, X from global (4-deep rotating prefetch) ----
#pragma unroll
        for (int kk = 0; kk < KC; kk += 4) {
            const int k = k0 + kk;
            float4 t0, t1;
            XLD(t0, t1, k + 4); FMA64(kk + 0, xa0, xa1); xa0 = t0; xa1 = t1;
            XLD(t0, t1, k + 5); FMA64(kk + 1, xb0, xb1); xb0 = t0; xb1 = t1;
            XLD(t0, t1, k + 6); FMA64(kk + 2, xc0, xc1); xc0 = t0; xc1 = t1;
            XLD(t0, t1, k + 7); FMA64(kk + 3, xd0, xd1); xd0 = t0; xd1 = t1;
        }
        __syncthreads();
    }

    // ---- epilogue: 4 passes over 16-row bands; exchange streams via LDS ----
    const int rhme  = lr >> 4;        // which 16-row band this lane's frag is in
    const int rbase = lr & 15;        // 0 or 8

    float wrow[NN];
#pragma unroll
    for (int j = 0; j < NN; ++j) wrow[j] = wmat[i * NN + j];

#pragma unroll
    for (int rh = 0; rh < 4; ++rh) {
        if (rhme == rh) {
            float* Eb = Es + wv * (16 * SPAD) + lc;
#pragma unroll
            for (int r = 0; r < 8; ++r) {
                *(float4*)(Eb + (rbase + r) * SPAD) =
                    make_float4(acc[r][0], acc[r][1], acc[r][2], acc[r][3]);
                *(float4*)(Eb + (rbase + r) * SPAD + 4) =
                    make_float4(acc[r][4], acc[r][5], acc[r][6], acc[r][7]);
            }
        }
        __syncthreads();

        if (tid < 256) {
            const int row  = tid >> 4;           // 0..15
            const int colq = (tid & 15) << 2;    // 0..60
            const int c    = c0 + rh * 16 + row;
            const float bias = conv_b[i * CCH + c];

            const float4 T = *(const float4*)(Es + 5 * (16 * SPAD) + row * SPAD + colq);
            const float Tv[4] = {T.x, T.y, T.z, T.w};

            float num[4] = {0.f, 0.f, 0.f, 0.f};
            float sq [4] = {0.f, 0.f, 0.f, 0.f};
#pragma unroll
            for (int j = 0; j < NN; ++j) {
                const float4 s  = *(const float4*)(Es + j * (16 * SPAD) + row * SPAD + colq);
                const float4 xj = *(const float4*)(
                    x + (size_t)((j * BB + b) * CCH + c) * HWD + hw0 + colq);
                const float sv[4] = {s.x, s.y, s.z, s.w};
                const float xv[4] = {xj.x, xj.y, xj.z, xj.w};
#pragma unroll
                for (int cc = 0; cc < 4; ++cc) {
                    const float target = sv[cc] + Tv[cc] + bias;
                    const float dist   = xv[cc] - target;
                    const float z      = dist * wrow[j];
                    float e = 1.0f / (1.0f + expf(-z));
                    e = (e > THRESH_V) ? e : 0.0f;
                    sq[cc]  = fmaf(e, e, sq[cc]);
                    num[cc] = fmaf(e, xv[cc], num[cc]);
                }
            }
            float4 res;
            res.x = num[0] / fmaxf(sqrtf(sq[0]), EPS_V);
            res.y = num[1] / fmaxf(sqrtf(sq[1]), EPS_V);
            res.z = num[2] / fmaxf(sqrtf(sq[2]), EPS_V);
            res.w = num[3] / fmaxf(sqrtf(sq[3]), EPS_V);
            *(float4*)(out + (size_t)((i * BB + b) * CCH + c) * HWD + hw0 + colq) = res;
        }
        __syncthreads();
    }
}

extern "C" void kernel_launch(void* const* d_in, const int* in_sizes, int n_in,
                              void* d_out, int out_size, void* d_ws, size_t ws_size,
                              hipStream_t stream) {
    const float* x      = (const float*)d_in[0];
    const float* w      = (const float*)d_in[1];
    const float* conv_w = (const float*)d_in[2];
    const float* conv_b = (const float*)d_in[3];
    float* out = (float*)d_out;
    float* ws  = (float*)d_ws;   // needs 2*5*256*256*4 B = 2.62 MB

    // prep: 5*256*64 = 81920 work items
    fub_prep<<<dim3(320), dim3(256), 0, stream>>>(conv_w, ws);

    // grid: hwt(16) * b(4) * ct(4) * i(5) = 1280 blocks of 384 threads
    fub_main<<<dim3(1280), dim3(384), 0, stream>>>(x, w, ws, conv_b, out);
}

// Round 8
// 328.093 us; speedup vs baseline: 1.1555x; 1.1555x over previous
//
#include <hip/hip_runtime.h>
#include <cmath>

// Problem constants (from reference)
#define NN  5      // N_NODES
#define BB  4      // batch
#define CCH 256    // channels
#define HWD 1024   // H*W
#define THRESH_V 0.3f
#define EPS_V 1e-12f

// R8: R1's all-LDS structure (empirically best: 301us) with the ONE change
// that was never cleanly tested: KC=32 -> 16, shrinking LDS 58KB -> 29KB so
// 4 blocks (24 waves) fit per CU instead of 1-2. R1/R5/R6/R7 all show
// wall = 2x VALU-busy at ~6-9 waves/CU -- latency-bound, not pipe-bound
// (R1's LDS-pipe demand = 154us, only 51% of its 301us). R2 tried KC=16 but
// died to the (384,6) register cap (40 VGPR, 7GB scratch); here we keep the
// proven (384,3) budget (R1: 84 VGPR, zero scratch).
// Stage reads A/W2 from the ws-pretransposed [i][k][c] tables (R3-verified
// prep) -> pure float4 copies, no in-kernel transpose.

#define CT 64      // channel rows per block
#define WT 64      // hw cols per block
#define KC 16      // k chunk
#define APAD 68    // As/W2s row stride (floats)
#define SPAD 68    // Es row stride (floats) in epilogue

#define W2T_OFF (NN * CCH * CCH)          // second table in ws

// smem layout (floats):
//   staging: Xs[5][16][64] @0 (5120) | As[16][68] @5120 (1088) | W2s @6208 (1088)
//   epilogue overlay: Es[6][16][68] @0 (6528)
#define XS_FLOATS (NN * KC * WT)          // 5120
#define AS_OFF    XS_FLOATS               // 5120
#define W2S_OFF   (AS_OFF + KC * APAD)    // 6208
#define SMEM_FLOATS (W2S_OFF + KC * APAD) // 7296 floats = 29184 B

// ---------------- prep: transpose conv_w into ws (verified R3) ----------------
// ws: At[i][k][c] = W1[i][c][k] + W2[i][c][k];  W2t[i][k][c] = W2[i][c][k]
__global__ void fub_prep(const float* __restrict__ conv_w, float* __restrict__ ws)
{
    const int t = blockIdx.x * 256 + threadIdx.x;   // 0 .. 5*256*64-1
    if (t >= NN * CCH * 64) return;
    const int c4 = (t & 63) << 2;        // c base 0..252
    const int k  = (t >> 6) & 255;       // 0..255
    const int i  = t >> 14;              // 0..4
    float s1[4], s2[4];
#pragma unroll
    for (int cc = 0; cc < 4; ++cc) {
        const float* p = conv_w + (size_t)(i * CCH + c4 + cc) * (2 * CCH) + k;
        const float w1 = p[0];
        const float w2 = p[CCH];
        s1[cc] = w1 + w2;
        s2[cc] = w2;
    }
    float* At  = ws + (size_t)(i * CCH + k) * CCH + c4;
    float* W2t = ws + W2T_OFF + (size_t)(i * CCH + k) * CCH + c4;
    *(float4*)At  = make_float4(s1[0], s1[1], s1[2], s1[3]);
    *(float4*)W2t = make_float4(s2[0], s2[1], s2[2], s2[3]);
}

// ---------------- main ----------------
__global__ __launch_bounds__(384, 3)
void fub_main(const float* __restrict__ x, const float* __restrict__ wmat,
              const float* __restrict__ ws, const float* __restrict__ conv_b,
              float* __restrict__ out)
{
    __shared__ __align__(16) float smem[SMEM_FLOATS];
    float* Xs  = smem;                 // [5][KC][WT]
    float* As  = smem + AS_OFF;        // [KC][APAD]
    float* W2s = smem + W2S_OFF;       // [KC][APAD]
    float* Es  = smem;                 // [6][16][SPAD] overlay (epilogue only)

    const int tid  = threadIdx.x;
    const int wv   = tid >> 6;        // 0..5 : stream id
    const int lane = tid & 63;

    // XCD-chunked bijective swizzle (1280 % 8 == 0): the 20 blocks sharing one
    // x panel (b,hwt) land on one XCD's L2, A tables shared across all.
    const int wg  = blockIdx.x;
    int L = (wg & 7) * 160 + (wg >> 3);
    const int i   = L % 5;  L /= 5;
    const int ct  = L & 3;  L >>= 2;
    const int b   = L & 3;  L >>= 2;
    const int hwt = L;                 // 0..15

    const int c0  = ct * CT;
    const int hw0 = hwt * WT;

    const int lr = (lane >> 3) << 3;  // frag row base 0,8,...,56
    const int lc = (lane & 7)  << 3;  // frag col base 0,8,...,56

    // stream w<5: A_i @ x[w]; stream 5: W2_i @ x[i]
    const int jx = (wv < NN) ? wv : i;
    const float* Ms = (wv == 5) ? W2s : As;
    const float* Mb = Ms + lr;
    const float* Xb = Xs + jx * (KC * WT) + lc;

    float acc[8][8];
#pragma unroll
    for (int r = 0; r < 8; ++r)
#pragma unroll
        for (int c = 0; c < 8; ++c) acc[r][c] = 0.0f;

    for (int k0 = 0; k0 < CCH; k0 += KC) {
        // ---- stage: threads 0..255 load Xs (1280 float4, 5 each),
        //             threads 256..383 load As/W2s (512 float4, 4 each) ----
        if (tid < 256) {
#pragma unroll
            for (int it = 0; it < 5; ++it) {
                const int t   = tid + it * 256;       // 0..1279
                const int j   = t >> 8;               // 0..4
                const int rem = t & 255;
                const int kk  = rem >> 4;             // 0..15
                const int q4  = (rem & 15) << 2;      // 0..60
                const float4 v = *(const float4*)(
                    x + (size_t)((j * BB + b) * CCH + k0 + kk) * HWD + hw0 + q4);
                *(float4*)(Xs + j * (KC * WT) + kk * WT + q4) = v;
            }
        } else {
            const int u = tid - 256;                  // 0..127
#pragma unroll
            for (int it = 0; it < 4; ++it) {
                const int t   = u + it * 128;         // 0..511
                const int tbl = t >> 8;               // 0=A, 1=W2
                const int rem = t & 255;
                const int kk  = rem >> 4;             // 0..15
                const int c4  = (rem & 15) << 2;      // 0..60
                const float4 v = *(const float4*)(
                    ws + (size_t)(tbl ? W2T_OFF : 0)
                       + (size_t)(i * CCH + k0 + kk) * CCH + c0 + c4);
                *(float4*)((tbl ? W2s : As) + kk * APAD + c4) = v;
            }
        }
        __syncthreads();

        // ---- compute: both operands from LDS, 8x8 frag/lane ----
#pragma unroll 4
        for (int kk = 0; kk < KC; ++kk) {
            const float4 a0 = *(const float4*)(Mb + kk * APAD);
            const float4 a1 = *(const float4*)(Mb + kk * APAD + 4);
            const float4 x0 = *(const float4*)(Xb + kk * WT);
            const float4 x1 = *(const float4*)(Xb + kk * WT + 4);
            const float ar[8] = {a0.x, a0.y, a0.z, a0.w, a1.x, a1.y, a1.z, a1.w};
            const float xc[8] = {x0.x, x0.y, x0.z, x0.w, x1.x, x1.y, x1.z, x1.w};
#pragma unroll
            for (int r = 0; r < 8; ++r)
#pragma unroll
                for (int c = 0; c < 8; ++c)
                    acc[r][c] = fmaf(ar[r], xc[c], acc[r][c]);
        }
        __syncthreads();
    }

    // ---- epilogue: 4 passes over 16-row bands; exchange streams via LDS ----
    const int rhme  = lr >> 4;        // which 16-row band this lane's frag is in
    const int rbase = lr & 15;        // 0 or 8

    float wrow[NN];
#pragma unroll
    for (int j = 0; j < NN; ++j) wrow[j] = wmat[i * NN + j];

#pragma unroll
    for (int rh = 0; rh < 4; ++rh) {
        if (rhme == rh) {
            float* Eb = Es + wv * (16 * SPAD) + lc;
#pragma unroll
            for (int r = 0; r < 8; ++r) {
                *(float4*)(Eb + (rbase + r) * SPAD) =
                    make_float4(acc[r][0], acc[r][1], acc[r][2], acc[r][3]);
                *(float4*)(Eb + (rbase + r) * SPAD + 4) =
                    make_float4(acc[r][4], acc[r][5], acc[r][6], acc[r][7]);
            }
        }
        __syncthreads();

        if (tid < 256) {
            const int row  = tid >> 4;           // 0..15
            const int colq = (tid & 15) << 2;    // 0..60
            const int c    = c0 + rh * 16 + row;
            const float bias = conv_b[i * CCH + c];

            const float4 T = *(const float4*)(Es + 5 * (16 * SPAD) + row * SPAD + colq);
            const float Tv[4] = {T.x, T.y, T.z, T.w};

            float num[4] = {0.f, 0.f, 0.f, 0.f};
            float sq [4] = {0.f, 0.f, 0.f, 0.f};
#pragma unroll
            for (int j = 0; j < NN; ++j) {
                const float4 s  = *(const float4*)(Es + j * (16 * SPAD) + row * SPAD + colq);
                const float4 xj = *(const float4*)(
                    x + (size_t)((j * BB + b) * CCH + c) * HWD + hw0 + colq);
                const float sv[4] = {s.x, s.y, s.z, s.w};
                const float xv[4] = {xj.x, xj.y, xj.z, xj.w};
#pragma unroll
                for (int cc = 0; cc < 4; ++cc) {
                    const float target = sv[cc] + Tv[cc] + bias;
                    const float dist   = xv[cc] - target;
                    const float z      = dist * wrow[j];
                    float e = 1.0f / (1.0f + expf(-z));
                    e = (e > THRESH_V) ? e : 0.0f;
                    sq[cc]  = fmaf(e, e, sq[cc]);
                    num[cc] = fmaf(e, xv[cc], num[cc]);
                }
            }
            float4 res;
            res.x = num[0] / fmaxf(sqrtf(sq[0]), EPS_V);
            res.y = num[1] / fmaxf(sqrtf(sq[1]), EPS_V);
            res.z = num[2] / fmaxf(sqrtf(sq[2]), EPS_V);
            res.w = num[3] / fmaxf(sqrtf(sq[3]), EPS_V);
            *(float4*)(out + (size_t)((i * BB + b) * CCH + c) * HWD + hw0 + colq) = res;
        }
        __syncthreads();
    }
}

extern "C" void kernel_launch(void* const* d_in, const int* in_sizes, int n_in,
                              void* d_out, int out_size, void* d_ws, size_t ws_size,
                              hipStream_t stream) {
    const float* x      = (const float*)d_in[0];
    const float* w      = (const float*)d_in[1];
    const float* conv_w = (const float*)d_in[2];
    const float* conv_b = (const float*)d_in[3];
    float* out = (float*)d_out;
    float* ws  = (float*)d_ws;   // needs 2*5*256*256*4 B = 2.62 MB

    // prep: 5*256*64 = 81920 work items
    fub_prep<<<dim3(320), dim3(256), 0, stream>>>(conv_w, ws);

    // grid: hwt(16) * b(4) * ct(4) * i(5) = 1280 blocks of 384 threads
    fub_main<<<dim3(1280), dim3(384), 0, stream>>>(x, w, ws, conv_b, out);
}